// Round 11
// baseline (183.783 us; speedup 1.0000x reference)
//
#include <hip/hip_runtime.h>
#include <hip/hip_bf16.h>

#define BATCH 2
#define SEQ 2048
#define HIDDIM 2048
#define NHEADS 16
#define HDIM 128
#define QKVN 2304   // 2048 Q + 128 K + 128 V

typedef __attribute__((ext_vector_type(8))) short bf16x8;
typedef __attribute__((ext_vector_type(4))) short short4v;
typedef __attribute__((ext_vector_type(4))) float f32x4;
typedef __attribute__((ext_vector_type(16))) float f32x16;
typedef __attribute__((ext_vector_type(4))) unsigned u32x4;

__device__ __forceinline__ short f2bf(float f) {
  unsigned u = __builtin_bit_cast(unsigned, f);
  unsigned r = (u + 0x7fffu + ((u >> 16) & 1u)) >> 16;
  return (short)r;
}

__device__ __forceinline__ unsigned cvtpk_bf16(float a, float b) {
  unsigned r;
  asm("v_cvt_pk_bf16_f32 %0, %1, %2" : "=v"(r) : "v"(a), "v"(b));
  return r;  // lo16 = bf16(a), hi16 = bf16(b)
}

// swaps hi-32-lanes of a with lo-32-lanes of b (gfx950 V_PERMLANE32_SWAP_B32)
#define PLSWAP(a, b) asm("v_permlane32_swap_b32 %0, %1" : "+v"(a), "+v"(b))

__device__ __forceinline__ void gl_lds16(const void* g, void* l) {
  __builtin_amdgcn_global_load_lds(
      (const __attribute__((address_space(1))) void*)g,
      (__attribute__((address_space(3))) void*)l, 16, 0, 0);
}

__device__ __forceinline__ float max3f(float a, float b, float c) {
  return fmaxf(fmaxf(a, b), c);        // clang fuses to v_max3_f32
}
__device__ __forceinline__ float vmax16(const f32x16& v) {
  float a = max3f(v[0], v[1], v[2]);
  float b = max3f(v[3], v[4], v[5]);
  float c = max3f(v[6], v[7], v[8]);
  float d = max3f(v[9], v[10], v[11]);
  float e = max3f(v[12], v[13], v[14]);
  return fmaxf(max3f(a, b, c), max3f(d, e, v[15]));
}

// ---- fused prep: f32->bf16 casts (h, Wq|Wk|Wv, optionally Wo) + bias concat ----
__global__ void prep_kernel(const float* __restrict__ h, const float* __restrict__ Wq,
                            const float* __restrict__ Wk, const float* __restrict__ Wv,
                            const float* __restrict__ Wo,
                            const float* __restrict__ bq, const float* __restrict__ bk,
                            const float* __restrict__ bv,
                            short* __restrict__ h_bf, short* __restrict__ Wqkv_bf,
                            short* __restrict__ Wo_bf, float* __restrict__ bqkv)
{
  int bid = blockIdx.x;
  const float* src;
  short* dst;
  int n;
  if (bid < 8192)        { src = h;  dst = h_bf;                n = 8388608; }
  else if (bid < 12288)  { src = Wq; dst = Wqkv_bf;             n = 4194304; bid -= 8192; }
  else if (bid < 12544)  { src = Wk; dst = Wqkv_bf + 4194304;   n = 262144;  bid -= 12288; }
  else if (bid < 12800)  { src = Wv; dst = Wqkv_bf + 4456448;   n = 262144;  bid -= 12544; }
  else if (bid < 12809) {
    int i = (bid - 12800) * 256 + threadIdx.x;
    if (i < QKVN) {
      float v;
      if (i < HIDDIM) v = bq[i];
      else if (i < HIDDIM + HDIM) v = bk[i - HIDDIM];
      else v = bv[i - HIDDIM - HDIM];
      bqkv[i] = v;
    }
    return;
  }
  else                   { src = Wo; dst = Wo_bf;               n = 4194304; bid -= 12809; }
  int i = (bid * 256 + threadIdx.x) * 4;
  if (i >= n) return;
  float4 v = *(const float4*)(src + i);
  short4v o;
  o[0] = f2bf(v.x); o[1] = f2bf(v.y); o[2] = f2bf(v.z); o[3] = f2bf(v.w);
  *(short4v*)(dst + i) = o;
}

// ---- f32 -> bf16 cast (fallback Wo path when ws is too small for a separate slot) ----
__global__ void cvt_kernel(const float* __restrict__ in, short* __restrict__ out, int n) {
  int i = (blockIdx.x * blockDim.x + threadIdx.x) * 4;
  if (i >= n) return;
  float4 v = *(const float4*)(in + i);
  short4v o;
  o[0] = f2bf(v.x); o[1] = f2bf(v.y); o[2] = f2bf(v.z); o[3] = f2bf(v.w);
  *(short4v*)(out + i) = o;
}

// ---- C = A[M,K] @ W[N,K]^T + bias.
// MODE 0: f32 C at row*N+col (single stacked GEMM, no batch z)
// MODE 3: QKV epilogue: Q cols (<2048) pre-scaled by 1/sqrt(128)*log2(e) and ->bf16
//         Cv[row*QKVN+col]; K cols ->bf16 Cv; V cols -> Vt[(col-2176)*(B*S)+row]
// launch_bounds (256,3): 3 blocks/CU (12 waves/CU). Grid nwg % 8 == 0 (XCD swizzle).
template <int MODE>
__global__ __launch_bounds__(256, 3)
void gemm_bt(const short* __restrict__ A, const short* __restrict__ W,
             const float* __restrict__ bias, void* __restrict__ Cv, void* __restrict__ Cv2,
             int M, int N, int K)
{
  __shared__ short As[128 * 64];
  __shared__ short Ws[128 * 64];
  const int tid = threadIdx.x;
  const int lane = tid & 63;
  const int w = tid >> 6;
  const int wr = w >> 1, wc = w & 1;

  // bijective XCD-aware swizzle (m204 form; nwg % 8 == 0): XCD k owns a
  // contiguous run of flat tile ids -> A-panels/W-panels stay in its L2.
  const int gx = gridDim.x;
  const int nwg = gx * gridDim.y;
  const int id = blockIdx.y * gx + blockIdx.x;
  const int cpx = nwg >> 3;
  const int swz = (id & 7) * cpx + (id >> 3);
  const int tn = (swz % gx) * 128, tm = (swz / gx) * 128;

  const int rA = lane & 15;
  const int r7 = rA & 7;
  const int srow = lane >> 3;            // row within 1KB chunk (rows are 128B)
  const int scg  = (lane & 7) ^ srow;    // pre-swizzled source 16B-group

  f32x4 acc[4][4] = {};

  for (int k0 = 0; k0 < K; k0 += 64) {
    __syncthreads();
#pragma unroll
    for (int i = 0; i < 4; ++i) {
      int ch = w * 4 + i;                // 16 chunks of 1KB per tile
      gl_lds16(A + (size_t)(tm + ch * 8 + srow) * K + k0 + scg * 8, As + ch * 512);
      gl_lds16(W + (size_t)(tn + ch * 8 + srow) * K + k0 + scg * 8, Ws + ch * 512);
    }
    __syncthreads();
#pragma unroll
    for (int kk = 0; kk < 64; kk += 32) {
      const int cg = (kk >> 3) + (lane >> 4);
      const int co = ((cg ^ r7) << 3);
      bf16x8 af[4];
#pragma unroll
      for (int mi = 0; mi < 4; ++mi)
        af[mi] = *(const bf16x8*)(As + ((wr * 64 + mi * 16 + rA) << 6) + co);
#pragma unroll
      for (int ni = 0; ni < 4; ++ni) {
        bf16x8 wf = *(const bf16x8*)(Ws + ((wc * 64 + ni * 16 + rA) << 6) + co);
#pragma unroll
        for (int mi = 0; mi < 4; ++mi)
          acc[mi][ni] = __builtin_amdgcn_mfma_f32_16x16x32_bf16(af[mi], wf, acc[mi][ni], 0, 0, 0);
      }
    }
  }

  const float QSCALE = 0.12752600954427384f;  // (1/sqrt(128)) * log2(e)
  const int cr = (lane >> 4) * 4;
  const int cc = lane & 15;
#pragma unroll
  for (int ni = 0; ni < 4; ++ni) {
    int col = tn + wc * 64 + ni * 16 + cc;
    float bv = bias[col];
#pragma unroll
    for (int mi = 0; mi < 4; ++mi) {
#pragma unroll
      for (int r = 0; r < 4; ++r) {
        int row = tm + wr * 64 + mi * 16 + cr + r;
        float v = acc[mi][ni][r] + bv;
        if constexpr (MODE == 0) {
          ((float*)Cv)[(size_t)row * N + col] = v;
        } else {
          if (col < HIDDIM)
            ((short*)Cv)[(size_t)row * QKVN + col] = f2bf(v * QSCALE);
          else if (col < HIDDIM + HDIM)
            ((short*)Cv)[(size_t)row * QKVN + col] = f2bf(v);
          else
            ((short*)Cv2)[(size_t)(col - HIDDIM - HDIM) * (BATCH * SEQ) + row] = f2bf(v);
        }
      }
    }
  }
}

// ---- fused multi-query attention (mask contributes <= 1e-9: skipped) ----
// grid (qtile=16, head=16, batch=2) = 512 blocks, 256 threads = 4 waves,
// 32 q-rows/wave, kv=64 chunks (32 chunks), DOUBLE-buffered (64 KB LDS ->
// 2 blocks/CU): prefetch (stage next while computing current, 1 barrier/chunk)
// PLUS cross-block phase decoupling (independent barriers anti-align, so one
// block's MFMA covers the other's softmax/VALU phase). Swapped 32x32x16 MFMAs,
// in-register softmax (Q pre-scaled, log2 domain), per-kv-slice interleave.
// K chunk: [64 kv][128 d], rows 256B = 16 slots, XOR ^(row&15).
// V chunk: 64 phys rows x 256B holding d and d+64 halves (R8 layout, verified):
// slot = (d>=64)*8 + kv/8, phys_slot = slot ^ (r&15); same involution on the
// pre-swizzled global source.
__global__ __launch_bounds__(256, 2)
void attn_kernel(const short* __restrict__ QKV, const short* __restrict__ Vt,
                 short* __restrict__ OT)
{
  __shared__ short smem[2][16384];      // [buf][Ks 8192 | Vs 8192]
  const int tid = threadIdx.x;          // 0..255
  const int l31 = tid & 31;
  const int hi2 = (tid >> 5) & 1;       // lane half
  const int w = tid >> 6;               // wave 0..3 -> q-block
  const int b = blockIdx.z, h = blockIdx.y, qt = blockIdx.x;
  const int rx = l31 & 15;              // swizzle row-index (rows step by 32)
  const short* Kp = QKV + HIDDIM;

  // stage pointers: 4 K-slots + 4 V-slots of 16B per thread (slot = tid + 256*i),
  // inverse-swizzled global source; LDS dest wave-uniform base (+ lane*16 implicit)
  const short* kp[4];
  const short* vp[4];
  {
#pragma unroll
    for (int i = 0; i < 4; ++i) {
      int s = tid + 256 * i;            // 0..1023
      int r = s >> 4;                   // 0..63
      int g = (s & 15) ^ (r & 15);      // pre-swizzled source slot
      kp[i] = Kp + (size_t)(b * SEQ + r) * QKVN + g * 8;
      int d = (g >> 3) * 64 + r;        // V logical: d-half bit + kv-slot
      int e = g & 7;
      vp[i] = Vt + (size_t)d * (BATCH * SEQ) + b * SEQ + e * 8;
    }
  }

  // Q fragments: B-operand layout (col q = l31, k(d) = kk*16 + hi2*8 + j)
  bf16x8 qf[8];
  {
    const short* Qp = QKV + (size_t)(b * SEQ + qt * 128 + w * 32 + l31) * QKVN + h * HDIM;
#pragma unroll
    for (int kk = 0; kk < 8; ++kk)
      qf[kk] = *(const bf16x8*)(Qp + kk * 16 + hi2 * 8);
  }

  f32x16 o[4] = {};                     // O^T: d rows (4 blocks of 32), col q = l31
  float m = -1e30f, l = 0.f;

#define STAGE(BUF)                                                          \
  { short* nb = (short*)smem[BUF];                                          \
    _Pragma("unroll")                                                       \
    for (int i = 0; i < 4; ++i) {                                           \
      gl_lds16(kp[i], nb + (w * 64 + 256 * i) * 8);                         \
      gl_lds16(vp[i], nb + 8192 + (w * 64 + 256 * i) * 8);                  \
      kp[i] += 64 * QKVN; vp[i] += 64;                                      \
    } }

  STAGE(0);
  __syncthreads();                      // buf0 ready

  for (int c = 0; c < 32; ++c) {
    const short* Ks = smem[c & 1];
    const short* Vs = smem[c & 1] + 8192;
    if (c < 31) STAGE((c + 1) & 1);

    // QK^T (swapped): s2[n] = K-block-n x Q^T -> S^T[kv][q], col q = l31,
    // row kv-in-32 = (r&3)+8*(r>>2)+4*hi2. Scores already in log2 domain.
    f32x16 s2[2] = {};
    __builtin_amdgcn_s_setprio(1);
#pragma unroll
    for (int n = 0; n < 2; ++n) {
      const int row = n * 32 + l31;
      bf16x8 kf[8];
#pragma unroll
      for (int kk = 0; kk < 8; ++kk)
        kf[kk] = *(const bf16x8*)(Ks + row * 128 + (((kk * 2 + hi2) ^ rx) << 3));
#pragma unroll
      for (int kk = 0; kk < 8; ++kk)
        s2[n] = __builtin_amdgcn_mfma_f32_32x32x16_bf16(kf[kk], qf[kk], s2[n], 0, 0, 0);
    }
    __builtin_amdgcn_s_setprio(0);

    // in-register online softmax (per-lane q-row; partner half via shfl_xor 32)
    float mx = fmaxf(vmax16(s2[0]), vmax16(s2[1]));
    mx = fmaxf(mx, __shfl_xor(mx, 32));
    if (!__all(mx <= m + 8.f)) {        // defer-max (T13): fires ~only on chunk 0
      float mn = fmaxf(m, mx);
      float cf = __builtin_amdgcn_exp2f(m - mn);
      m = mn; l *= cf;
#pragma unroll
      for (int nd = 0; nd < 4; ++nd)
#pragma unroll
        for (int r = 0; r < 16; ++r) o[nd][r] *= cf;
    }

    // per-kv-slice: {exp + pack (VALU)} then its 8 PV MFMAs (batched V reads)
    float rs = 0.f;
#pragma unroll
    for (int n = 0; n < 2; ++n) {
      float p[16];
#pragma unroll
      for (int r = 0; r < 16; ++r)
        p[r] = __builtin_amdgcn_exp2f(s2[n][r] - m);
      // tree-sum (short dep chains)
      rs += (((p[0] + p[1]) + (p[2] + p[3])) + ((p[4] + p[5]) + (p[6] + p[7])))
          + (((p[8] + p[9]) + (p[10] + p[11])) + ((p[12] + p[13]) + (p[14] + p[15])));
      unsigned w0 = cvtpk_bf16(p[0], p[1]),  w1 = cvtpk_bf16(p[2], p[3]);
      unsigned w2 = cvtpk_bf16(p[4], p[5]),  w3 = cvtpk_bf16(p[6], p[7]);
      unsigned w4 = cvtpk_bf16(p[8], p[9]),  w5 = cvtpk_bf16(p[10], p[11]);
      unsigned w6 = cvtpk_bf16(p[12], p[13]), w7 = cvtpk_bf16(p[14], p[15]);
      PLSWAP(w0, w2); PLSWAP(w1, w3);   // frag kv 0..15 : [w0,w1,w2,w3]
      PLSWAP(w4, w6); PLSWAP(w5, w7);   // frag kv 16..31: [w4,w5,w6,w7]
      bf16x8 pa0 = __builtin_bit_cast(bf16x8, (u32x4){w0, w1, w2, w3});
      bf16x8 pa1 = __builtin_bit_cast(bf16x8, (u32x4){w4, w5, w6, w7});
      // PV for this kv-slice: O^T[d][q] += V^T[d][kv] * P^T[kv][q]
      bf16x8 vf[8];
#pragma unroll
      for (int nd = 0; nd < 4; ++nd) {
        const int r2 = (nd & 1) * 32 + l31;       // phys row (d mod 64)
        const int ph = (nd >> 1) * 8;             // d-half slot offset
        vf[nd * 2]     = *(const bf16x8*)(Vs + r2 * 128 +
                          (((ph + (n * 2) * 2 + hi2) ^ rx) << 3));
        vf[nd * 2 + 1] = *(const bf16x8*)(Vs + r2 * 128 +
                          (((ph + (n * 2 + 1) * 2 + hi2) ^ rx) << 3));
      }
      __builtin_amdgcn_s_setprio(1);
#pragma unroll
      for (int nd = 0; nd < 4; ++nd) {
        o[nd] = __builtin_amdgcn_mfma_f32_32x32x16_bf16(vf[nd * 2], pa0, o[nd], 0, 0, 0);
        o[nd] = __builtin_amdgcn_mfma_f32_32x32x16_bf16(vf[nd * 2 + 1], pa1, o[nd], 0, 0, 0);
      }
      __builtin_amdgcn_s_setprio(0);
    }
    rs += __shfl_xor(rs, 32);
    l += rs;
    __syncthreads();                    // single barrier: drains stage vmcnt + LDS reuse
  }
#undef STAGE

  // epilogue: normalize, coalesced scalar stores of OT[h*128+d][q]
  const float inv = 1.f / l;
  short* dst = OT + (size_t)b * (SEQ * HIDDIM) + (size_t)(h * HDIM) * SEQ
             + qt * 128 + w * 32 + l31;
#pragma unroll
  for (int nd = 0; nd < 4; ++nd) {
#pragma unroll
    for (int r = 0; r < 16; ++r) {
      int d = nd * 32 + (r & 3) + 8 * (r >> 2) + 4 * hi2;
      dst[(size_t)d * SEQ] = f2bf(o[nd][r] * inv);
    }
  }
}

extern "C" void kernel_launch(void* const* d_in, const int* in_sizes, int n_in,
                              void* d_out, int out_size, void* d_ws, size_t ws_size,
                              hipStream_t stream)
{
  const float* hidden = (const float*)d_in[0];
  // d_in[1] = attention_mask : unused (scaled by -1e-9 in reference, negligible)
  const float* Wq = (const float*)d_in[2];
  const float* bq = (const float*)d_in[3];
  const float* Wk = (const float*)d_in[4];
  const float* bk = (const float*)d_in[5];
  const float* Wv = (const float*)d_in[6];
  const float* bv = (const float*)d_in[7];
  const float* Wo = (const float*)d_in[8];
  const float* bo = (const float*)d_in[9];
  float* out = (float*)d_out;

  // workspace layout (shorts), with aliasing to stay compact:
  //   QKV [4096][2304]              : 9437184   (fallback Wo_bf aliases this)
  //   Vt  [128][4096]               : 524288
  //   h_bf[4096][2048]              : 8388608   (OT aliases this after QKV gemm)
  //   Wqkv_bf [2304][2048]          : 4718592
  //   bqkv float[2304]              : 4608 (short-equiv)
  //   Wo_sep [2048][2048]           : 4194304 (only if ws_size allows)
  short* ws      = (short*)d_ws;
  short* QKV     = ws;
  short* Vt_bf   = ws + 9437184;
  short* h_bf    = Vt_bf + 524288;
  short* OT      = h_bf;                       // alias (h dead after QKV gemm)
  short* Wqkv_bf = h_bf + 8388608;
  float* bqkv    = (float*)(Wqkv_bf + 4718592);
  short* Wo_sep  = (short*)(bqkv + QKVN);

  const bool sep = ws_size >= (size_t)54535168;  // room for non-aliased Wo slot
  short* Wo_bf = sep ? Wo_sep : QKV;             // fallback: alias dead-QKV space

  // fused prep: h, Wq, Wk, Wv casts + bias concat (+ Wo cast when sep)
  prep_kernel<<<sep ? 16905 : 12809, 256, 0, stream>>>(
      hidden, Wq, Wk, Wv, Wo, bq, bk, bv, h_bf, Wqkv_bf, Wo_bf, bqkv);

  // QKV = h @ [Wq|Wk|Wv]^T + bqkv  (Q pre-scaled by 1/sqrt(128)*log2e; V transposed)
  gemm_bt<3><<<dim3(18, 32, 1), 256, 0, stream>>>(h_bf, Wqkv_bf, bqkv, QKV, Vt_bf,
                                                  4096, QKVN, 2048);
  // attention -> OT[b][h*128+d][s] bf16 (= stacked [4096][2048] matrix)
  attn_kernel<<<dim3(16, 16, 2), 256, 0, stream>>>(QKV, Vt_bf, OT);
  // Wo cast fallback (only when no separate slot: QKV space is dead now)
  if (!sep) cvt_kernel<<<4096, 256, 0, stream>>>(Wo, Wo_bf, 4194304);
  // out = OT_stacked @ Wo^T + bo -> f32 [4096][2048] == d_out [2][2048][2048]
  // (reference's reshape quirk: contraction over s)
  gemm_bt<0><<<dim3(16, 32, 1), 256, 0, stream>>>(OT, Wo_bf, bo, out, nullptr,
                                                  4096, 2048, 2048);
}

// Round 12
// 178.493 us; speedup vs baseline: 1.0296x; 1.0296x over previous
//
#include <hip/hip_runtime.h>
#include <hip/hip_bf16.h>

#define BATCH 2
#define SEQ 2048
#define HIDDIM 2048
#define NHEADS 16
#define HDIM 128
#define QKVN 2304   // 2048 Q + 128 K + 128 V

typedef __attribute__((ext_vector_type(8))) short bf16x8;
typedef __attribute__((ext_vector_type(4))) short short4v;
typedef __attribute__((ext_vector_type(4))) float f32x4;
typedef __attribute__((ext_vector_type(16))) float f32x16;
typedef __attribute__((ext_vector_type(4))) unsigned u32x4;

__device__ __forceinline__ short f2bf(float f) {
  unsigned u = __builtin_bit_cast(unsigned, f);
  unsigned r = (u + 0x7fffu + ((u >> 16) & 1u)) >> 16;
  return (short)r;
}

__device__ __forceinline__ unsigned cvtpk_bf16(float a, float b) {
  unsigned r;
  asm("v_cvt_pk_bf16_f32 %0, %1, %2" : "=v"(r) : "v"(a), "v"(b));
  return r;  // lo16 = bf16(a), hi16 = bf16(b)
}

// swaps hi-32-lanes of a with lo-32-lanes of b (gfx950 V_PERMLANE32_SWAP_B32)
#define PLSWAP(a, b) asm("v_permlane32_swap_b32 %0, %1" : "+v"(a), "+v"(b))

__device__ __forceinline__ void gl_lds16(const void* g, void* l) {
  __builtin_amdgcn_global_load_lds(
      (const __attribute__((address_space(1))) void*)g,
      (__attribute__((address_space(3))) void*)l, 16, 0, 0);
}

__device__ __forceinline__ float max3f(float a, float b, float c) {
  return fmaxf(fmaxf(a, b), c);        // clang fuses to v_max3_f32
}
__device__ __forceinline__ float vmax16(const f32x16& v) {
  float a = max3f(v[0], v[1], v[2]);
  float b = max3f(v[3], v[4], v[5]);
  float c = max3f(v[6], v[7], v[8]);
  float d = max3f(v[9], v[10], v[11]);
  float e = max3f(v[12], v[13], v[14]);
  return fmaxf(max3f(a, b, c), max3f(d, e, v[15]));
}

// ---- fused prep: f32->bf16 casts (h, Wq|Wk|Wv, optionally Wo) + bias concat ----
__global__ void prep_kernel(const float* __restrict__ h, const float* __restrict__ Wq,
                            const float* __restrict__ Wk, const float* __restrict__ Wv,
                            const float* __restrict__ Wo,
                            const float* __restrict__ bq, const float* __restrict__ bk,
                            const float* __restrict__ bv,
                            short* __restrict__ h_bf, short* __restrict__ Wqkv_bf,
                            short* __restrict__ Wo_bf, float* __restrict__ bqkv)
{
  int bid = blockIdx.x;
  const float* src;
  short* dst;
  int n;
  if (bid < 8192)        { src = h;  dst = h_bf;                n = 8388608; }
  else if (bid < 12288)  { src = Wq; dst = Wqkv_bf;             n = 4194304; bid -= 8192; }
  else if (bid < 12544)  { src = Wk; dst = Wqkv_bf + 4194304;   n = 262144;  bid -= 12288; }
  else if (bid < 12800)  { src = Wv; dst = Wqkv_bf + 4456448;   n = 262144;  bid -= 12544; }
  else if (bid < 12809) {
    int i = (bid - 12800) * 256 + threadIdx.x;
    if (i < QKVN) {
      float v;
      if (i < HIDDIM) v = bq[i];
      else if (i < HIDDIM + HDIM) v = bk[i - HIDDIM];
      else v = bv[i - HIDDIM - HDIM];
      bqkv[i] = v;
    }
    return;
  }
  else                   { src = Wo; dst = Wo_bf;               n = 4194304; bid -= 12809; }
  int i = (bid * 256 + threadIdx.x) * 4;
  if (i >= n) return;
  float4 v = *(const float4*)(src + i);
  short4v o;
  o[0] = f2bf(v.x); o[1] = f2bf(v.y); o[2] = f2bf(v.z); o[3] = f2bf(v.w);
  *(short4v*)(dst + i) = o;
}

// ---- f32 -> bf16 cast (fallback Wo path when ws is too small for a separate slot) ----
__global__ void cvt_kernel(const float* __restrict__ in, short* __restrict__ out, int n) {
  int i = (blockIdx.x * blockDim.x + threadIdx.x) * 4;
  if (i >= n) return;
  float4 v = *(const float4*)(in + i);
  short4v o;
  o[0] = f2bf(v.x); o[1] = f2bf(v.y); o[2] = f2bf(v.z); o[3] = f2bf(v.w);
  *(short4v*)(out + i) = o;
}

// ---- C = A[M,K] @ W[N,K]^T + bias.
// MODE 0: f32 C at row*N+col (single stacked GEMM, no batch z)
// MODE 3: QKV epilogue: Q cols (<2048) pre-scaled by 1/sqrt(128)*log2(e) and ->bf16
//         Cv[row*QKVN+col]; K cols ->bf16 Cv; V cols -> Vt[(col-2176)*(B*S)+row]
// launch_bounds (256,3): 3 blocks/CU (12 waves/CU). Grid nwg % 8 == 0 (XCD swizzle).
template <int MODE>
__global__ __launch_bounds__(256, 3)
void gemm_bt(const short* __restrict__ A, const short* __restrict__ W,
             const float* __restrict__ bias, void* __restrict__ Cv, void* __restrict__ Cv2,
             int M, int N, int K)
{
  __shared__ short As[128 * 64];
  __shared__ short Ws[128 * 64];
  const int tid = threadIdx.x;
  const int lane = tid & 63;
  const int w = tid >> 6;
  const int wr = w >> 1, wc = w & 1;

  // bijective XCD-aware swizzle (m204 form; nwg % 8 == 0): XCD k owns a
  // contiguous run of flat tile ids -> A-panels/W-panels stay in its L2.
  const int gx = gridDim.x;
  const int nwg = gx * gridDim.y;
  const int id = blockIdx.y * gx + blockIdx.x;
  const int cpx = nwg >> 3;
  const int swz = (id & 7) * cpx + (id >> 3);
  const int tn = (swz % gx) * 128, tm = (swz / gx) * 128;

  const int rA = lane & 15;
  const int r7 = rA & 7;
  const int srow = lane >> 3;            // row within 1KB chunk (rows are 128B)
  const int scg  = (lane & 7) ^ srow;    // pre-swizzled source 16B-group

  f32x4 acc[4][4] = {};

  for (int k0 = 0; k0 < K; k0 += 64) {
    __syncthreads();
#pragma unroll
    for (int i = 0; i < 4; ++i) {
      int ch = w * 4 + i;                // 16 chunks of 1KB per tile
      gl_lds16(A + (size_t)(tm + ch * 8 + srow) * K + k0 + scg * 8, As + ch * 512);
      gl_lds16(W + (size_t)(tn + ch * 8 + srow) * K + k0 + scg * 8, Ws + ch * 512);
    }
    __syncthreads();
#pragma unroll
    for (int kk = 0; kk < 64; kk += 32) {
      const int cg = (kk >> 3) + (lane >> 4);
      const int co = ((cg ^ r7) << 3);
      bf16x8 af[4];
#pragma unroll
      for (int mi = 0; mi < 4; ++mi)
        af[mi] = *(const bf16x8*)(As + ((wr * 64 + mi * 16 + rA) << 6) + co);
#pragma unroll
      for (int ni = 0; ni < 4; ++ni) {
        bf16x8 wf = *(const bf16x8*)(Ws + ((wc * 64 + ni * 16 + rA) << 6) + co);
#pragma unroll
        for (int mi = 0; mi < 4; ++mi)
          acc[mi][ni] = __builtin_amdgcn_mfma_f32_16x16x32_bf16(af[mi], wf, acc[mi][ni], 0, 0, 0);
      }
    }
  }

  const float QSCALE = 0.12752600954427384f;  // (1/sqrt(128)) * log2(e)
  const int cr = (lane >> 4) * 4;
  const int cc = lane & 15;
#pragma unroll
  for (int ni = 0; ni < 4; ++ni) {
    int col = tn + wc * 64 + ni * 16 + cc;
    float bv = bias[col];
#pragma unroll
    for (int mi = 0; mi < 4; ++mi) {
#pragma unroll
      for (int r = 0; r < 4; ++r) {
        int row = tm + wr * 64 + mi * 16 + cr + r;
        float v = acc[mi][ni][r] + bv;
        if constexpr (MODE == 0) {
          ((float*)Cv)[(size_t)row * N + col] = v;
        } else {
          if (col < HIDDIM)
            ((short*)Cv)[(size_t)row * QKVN + col] = f2bf(v * QSCALE);
          else if (col < HIDDIM + HDIM)
            ((short*)Cv)[(size_t)row * QKVN + col] = f2bf(v);
          else
            ((short*)Cv2)[(size_t)(col - HIDDIM - HDIM) * (BATCH * SEQ) + row] = f2bf(v);
        }
      }
    }
  }
}

// ---- fused multi-query attention (mask contributes <= 1e-9: skipped) ----
// grid (qtile=8, head=16, batch=2), 512 threads = 8 waves, 32 q-rows/wave.
// Best-measured structure (R9/R10, 76.8 us ~= 890 TF = plain-HIP attn plateau;
// five alternative schedules measured 77-82 us): K/V double-buffered kv=128,
// ONE barrier/chunk, swapped 32x32x16 MFMAs, in-register softmax (Q pre-scaled,
// log2 domain), per-kv-slice {exp/pack -> PV MFMA} interleave, batched reads.
__global__ __launch_bounds__(512, 2)
void attn_kernel(const short* __restrict__ QKV, const short* __restrict__ Vt,
                 short* __restrict__ OT)
{
  __shared__ short smem[2][32768];      // [buf][Ks 16384 | Vs 16384]
  const int tid = threadIdx.x;
  const int l31 = tid & 31;
  const int hi2 = (tid >> 5) & 1;       // lane half
  const int w = tid >> 6;               // wave 0..7 -> q-block
  const int b = blockIdx.z, h = blockIdx.y, qt = blockIdx.x;
  const int rx = l31 & 15;              // swizzle row-index (rows step by 32)
  const short* Kp = QKV + HIDDIM;

  // incremental stage pointers (advanced += per chunk; no mad64 per chunk)
  const short* kptr[4];
  const short* vptr[4];
  {
    const int rin = (tid & 63) >> 4;    // row within 1KB chunk
    const int gp = tid & 15;            // phys 16B group
#pragma unroll
    for (int i = 0; i < 4; ++i) {
      int ch = w * 4 + i;               // 0..31
      int row = ch * 4 + rin;           // 0..127
      int gl = gp ^ (row & 15);         // pre-swizzled source group
      kptr[i] = Kp + (size_t)(b * SEQ + row) * QKVN + gl * 8;
      vptr[i] = Vt + (size_t)row * (BATCH * SEQ) + b * SEQ + gl * 8;
    }
  }

  // Q fragments: B-operand layout (col q = l31, k(d) = kk*16 + hi2*8 + j)
  bf16x8 qf[8];
  {
    const short* Qp = QKV + (size_t)(b * SEQ + qt * 256 + w * 32 + l31) * QKVN + h * HDIM;
#pragma unroll
    for (int kk = 0; kk < 8; ++kk)
      qf[kk] = *(const bf16x8*)(Qp + kk * 16 + hi2 * 8);
  }

  f32x16 o[4] = {};                     // O^T: d rows (4 blocks of 32), col q = l31
  float m = -1e30f, l = 0.f;

  // stage chunk 0
#pragma unroll
  for (int i = 0; i < 4; ++i) {
    int ch = w * 4 + i;
    gl_lds16(kptr[i], (short*)smem[0] + ch * 512);
    gl_lds16(vptr[i], (short*)smem[0] + 16384 + ch * 512);
    kptr[i] += 128 * QKVN;
    vptr[i] += 128;
  }
  __syncthreads();

  for (int c = 0; c < 16; ++c) {
    const short* Ks = smem[c & 1];
    const short* Vs = smem[c & 1] + 16384;
    if (c < 15) {
      short* nb = smem[(c + 1) & 1];
#pragma unroll
      for (int i = 0; i < 4; ++i) {
        int ch = w * 4 + i;
        gl_lds16(kptr[i], nb + ch * 512);
        gl_lds16(vptr[i], nb + 16384 + ch * 512);
        kptr[i] += 128 * QKVN;
        vptr[i] += 128;
      }
    }

    // QK^T (swapped): s[n] = K-block-n x Q^T -> S^T[kv][q], col q = l31,
    // row kv-in-32 = (r&3)+8*(r>>2)+4*hi2. Scores already in log2 domain.
    f32x16 s[4] = {};
    __builtin_amdgcn_s_setprio(1);
#pragma unroll
    for (int n = 0; n < 4; ++n) {
      const int row = n * 32 + l31;
      bf16x8 kf[8];
#pragma unroll
      for (int kk = 0; kk < 8; ++kk)
        kf[kk] = *(const bf16x8*)(Ks + row * 128 + (((kk * 2 + hi2) ^ rx) << 3));
#pragma unroll
      for (int kk = 0; kk < 8; ++kk)
        s[n] = __builtin_amdgcn_mfma_f32_32x32x16_bf16(kf[kk], qf[kk], s[n], 0, 0, 0);
    }
    __builtin_amdgcn_s_setprio(0);

    // in-register online softmax (per-lane q-row; partner half via shfl_xor 32)
    float mx = fmaxf(fmaxf(vmax16(s[0]), vmax16(s[1])),
                     fmaxf(vmax16(s[2]), vmax16(s[3])));
    mx = fmaxf(mx, __shfl_xor(mx, 32));
    if (!__all(mx <= m + 8.f)) {        // defer-max (T13): fires ~only on chunk 0
      float mn = fmaxf(m, mx);
      float cf = __builtin_amdgcn_exp2f(m - mn);
      m = mn; l *= cf;
#pragma unroll
      for (int nd = 0; nd < 4; ++nd)
#pragma unroll
        for (int r = 0; r < 16; ++r) o[nd][r] *= cf;
    }

    // per-kv-slice: {exp + pack (VALU)} then its 8 PV MFMAs (batched V reads)
    // -> slice n+1's VALU overlaps slice n's MFMA execution.
    float rs = 0.f;
#pragma unroll
    for (int n = 0; n < 4; ++n) {
      float p[16];
#pragma unroll
      for (int r = 0; r < 16; ++r)
        p[r] = __builtin_amdgcn_exp2f(s[n][r] - m);
      // tree-sum (short dep chains)
      rs += (((p[0] + p[1]) + (p[2] + p[3])) + ((p[4] + p[5]) + (p[6] + p[7])))
          + (((p[8] + p[9]) + (p[10] + p[11])) + ((p[12] + p[13]) + (p[14] + p[15])));
      unsigned w0 = cvtpk_bf16(p[0], p[1]),  w1 = cvtpk_bf16(p[2], p[3]);
      unsigned w2 = cvtpk_bf16(p[4], p[5]),  w3 = cvtpk_bf16(p[6], p[7]);
      unsigned w4 = cvtpk_bf16(p[8], p[9]),  w5 = cvtpk_bf16(p[10], p[11]);
      unsigned w6 = cvtpk_bf16(p[12], p[13]), w7 = cvtpk_bf16(p[14], p[15]);
      PLSWAP(w0, w2); PLSWAP(w1, w3);   // frag kv 0..15 : [w0,w1,w2,w3]
      PLSWAP(w4, w6); PLSWAP(w5, w7);   // frag kv 16..31: [w4,w5,w6,w7]
      bf16x8 pa0 = __builtin_bit_cast(bf16x8, (u32x4){w0, w1, w2, w3});
      bf16x8 pa1 = __builtin_bit_cast(bf16x8, (u32x4){w4, w5, w6, w7});
      // PV for this kv-slice: O^T[d][q] += V^T[d][kv] * P^T[kv][q]
      bf16x8 vf[8];
#pragma unroll
      for (int nd = 0; nd < 4; ++nd) {
        const int row = nd * 32 + l31;
        vf[nd * 2]     = *(const bf16x8*)(Vs + row * 128 + ((((n * 2) * 2 + hi2) ^ rx) << 3));
        vf[nd * 2 + 1] = *(const bf16x8*)(Vs + row * 128 + ((((n * 2 + 1) * 2 + hi2) ^ rx) << 3));
      }
      __builtin_amdgcn_s_setprio(1);
#pragma unroll
      for (int nd = 0; nd < 4; ++nd) {
        o[nd] = __builtin_amdgcn_mfma_f32_32x32x16_bf16(vf[nd * 2], pa0, o[nd], 0, 0, 0);
        o[nd] = __builtin_amdgcn_mfma_f32_32x32x16_bf16(vf[nd * 2 + 1], pa1, o[nd], 0, 0, 0);
      }
      __builtin_amdgcn_s_setprio(0);
    }
    rs += __shfl_xor(rs, 32);
    l += rs;
    __syncthreads();                    // single barrier: drains stage vmcnt + LDS reuse
  }

  // epilogue: normalize, coalesced scalar stores of OT[h*128+d][q]
  const float inv = 1.f / l;
  short* dst = OT + (size_t)b * (SEQ * HIDDIM) + (size_t)(h * HDIM) * SEQ
             + qt * 256 + w * 32 + l31;
#pragma unroll
  for (int nd = 0; nd < 4; ++nd) {
#pragma unroll
    for (int r = 0; r < 16; ++r) {
      int d = nd * 32 + (r & 3) + 8 * (r >> 2) + 4 * hi2;
      dst[(size_t)d * SEQ] = f2bf(o[nd][r] * inv);
    }
  }
}

extern "C" void kernel_launch(void* const* d_in, const int* in_sizes, int n_in,
                              void* d_out, int out_size, void* d_ws, size_t ws_size,
                              hipStream_t stream)
{
  const float* hidden = (const float*)d_in[0];
  // d_in[1] = attention_mask : unused (scaled by -1e-9 in reference, negligible)
  const float* Wq = (const float*)d_in[2];
  const float* bq = (const float*)d_in[3];
  const float* Wk = (const float*)d_in[4];
  const float* bk = (const float*)d_in[5];
  const float* Wv = (const float*)d_in[6];
  const float* bv = (const float*)d_in[7];
  const float* Wo = (const float*)d_in[8];
  const float* bo = (const float*)d_in[9];
  float* out = (float*)d_out;

  // workspace layout (shorts), with aliasing to stay compact:
  //   QKV [4096][2304]              : 9437184   (fallback Wo_bf aliases this)
  //   Vt  [128][4096]               : 524288
  //   h_bf[4096][2048]              : 8388608   (OT aliases this after QKV gemm)
  //   Wqkv_bf [2304][2048]          : 4718592
  //   bqkv float[2304]              : 4608 (short-equiv)
  //   Wo_sep [2048][2048]           : 4194304 (only if ws_size allows)
  short* ws      = (short*)d_ws;
  short* QKV     = ws;
  short* Vt_bf   = ws + 9437184;
  short* h_bf    = Vt_bf + 524288;
  short* OT      = h_bf;                       // alias (h dead after QKV gemm)
  short* Wqkv_bf = h_bf + 8388608;
  float* bqkv    = (float*)(Wqkv_bf + 4718592);
  short* Wo_sep  = (short*)(bqkv + QKVN);

  const bool sep = ws_size >= (size_t)54535168;  // room for non-aliased Wo slot
  short* Wo_bf = sep ? Wo_sep : QKV;             // fallback: alias dead-QKV space

  // fused prep: h, Wq, Wk, Wv casts + bias concat (+ Wo cast when sep)
  prep_kernel<<<sep ? 16905 : 12809, 256, 0, stream>>>(
      hidden, Wq, Wk, Wv, Wo, bq, bk, bv, h_bf, Wqkv_bf, Wo_bf, bqkv);

  // QKV = h @ [Wq|Wk|Wv]^T + bqkv  (Q pre-scaled by 1/sqrt(128)*log2e; V transposed)
  gemm_bt<3><<<dim3(18, 32, 1), 256, 0, stream>>>(h_bf, Wqkv_bf, bqkv, QKV, Vt_bf,
                                                  4096, QKVN, 2048);
  // attention -> OT[b][h*128+d][s] bf16 (= stacked [4096][2048] matrix)
  attn_kernel<<<dim3(8, 16, 2), 512, 0, stream>>>(QKV, Vt_bf, OT);
  // Wo cast fallback (only when no separate slot: QKV space is dead now)
  if (!sep) cvt_kernel<<<4096, 256, 0, stream>>>(Wo, Wo_bf, 4194304);
  // out = OT_stacked @ Wo^T + bo -> f32 [4096][2048] == d_out [2][2048][2048]
  // (reference's reshape quirk: contraction over s)
  gemm_bt<0><<<dim3(16, 32, 1), 256, 0, stream>>>(OT, Wo_bf, bo, out, nullptr,
                                                  4096, 2048, 2048);
}